// Round 1
// 3824.458 us; speedup vs baseline: 1.3961x; 1.3961x over previous
//
#include <hip/hip_runtime.h>
#include <hip/hip_fp16.h>

typedef _Float16 f16;
typedef __attribute__((ext_vector_type(8))) _Float16 f16x8;
typedef __attribute__((ext_vector_type(4))) float f32x4;

// ---------------------------------------------------------------------------
// Core tile GEMM: C[128 x 64] = A[128 rows x K] * B(rows)[64 x K]^T
// A row-major (lda), B row-major (ldb); B tile row r -> global row
//   nbase + (r>>4)*nstride + (r&15)   (4 groups of 16 rows)
// Wave w (of 4) computes rows [w*32, w*32+32), all 64 cols as 2x4 16x16 tiles.
// acc[mt][nt][reg]: row = w*32 + mt*16 + (lane>>4)*4 + reg, col-in-grp = lane&15.
//
// BK=64, double-buffered LDS, depth-2 prefetch with COUNTED vmcnt (T3+T4):
//   prologue: stage tile0->buf0, tile1->buf1          (12 wave-loads in flight)
//   iter t  : s_waitcnt vmcnt(6)   -> tile t landed, tile t+1 stays in flight
//             s_barrier
//             ds_read_b128 frags from buf[t&1]; lgkmcnt(0); s_barrier (release)
//             stage tile t+2 -> buf[t&1]  (latency hides under MFMA + next iter)
//             16x mfma_f32_16x16x32_f16
// LDS layout: [row][8 chunks of 8 f16], chunk col XOR (row&7). global source is
// pre-swizzled so global_load_lds dest stays linear (HW: wave base + lane*16).
// Bank math: frag read addr = row*128B + c'*16B, row*128 == 0 mod 32 banks,
// c' = chunk^(row&7) spans 8 values over 8 rows -> 32 banks, 2-way = free.
// ---------------------------------------------------------------------------
__device__ __forceinline__ void gemm_core(
    const f16* __restrict__ A, int lda,
    const f16* __restrict__ Bm, int ldb,
    int K, int bm0, int nbase, int nstride,
    f16* As, f16* Bs, f32x4 acc[2][4])
{
    const int tid  = threadIdx.x;
    const int wave = tid >> 6;
    const int lane = tid & 63;
    const int l15  = lane & 15;
    const int quad = lane >> 4;

    #pragma unroll
    for (int mt = 0; mt < 2; ++mt)
      #pragma unroll
      for (int nt = 0; nt < 4; ++nt)
        acc[mt][nt] = (f32x4){0.f, 0.f, 0.f, 0.f};

    // A tile: 128 rows x 64 cols f16 = 1024 16B-chunks -> 4 passes of 256 thr
    const f16* gA[4];
    #pragma unroll
    for (int p = 0; p < 4; ++p) {
        int s = p * 256 + tid;
        int r = s >> 3;
        int cg = (s & 7) ^ (r & 7);           // pre-swizzled global chunk
        gA[p] = A + (size_t)(bm0 + r) * lda + cg * 8;
    }
    // B tile: 64 rows x 64 cols = 512 chunks -> 2 passes
    const f16* gB[2];
    #pragma unroll
    for (int p = 0; p < 2; ++p) {
        int s = p * 256 + tid;
        int r = s >> 3;
        int cg = (s & 7) ^ (r & 7);
        int brow = nbase + (r >> 4) * nstride + (r & 15);
        gB[p] = Bm + (size_t)brow * ldb + cg * 8;
    }
    // wave-uniform LDS destinations (HW writes base + lane*16)
    f16* ldsA[4];
    #pragma unroll
    for (int p = 0; p < 4; ++p) ldsA[p] = As + (p * 256 + wave * 64) * 8;
    f16* ldsB[2];
    #pragma unroll
    for (int p = 0; p < 2; ++p) ldsB[p] = Bs + (p * 256 + wave * 64) * 8;

    auto stage = [&](int buf, int k0) {   // 6 wave-loads per call
        #pragma unroll
        for (int p = 0; p < 4; ++p)
            __builtin_amdgcn_global_load_lds(
                (const __attribute__((address_space(1))) void*)(gA[p] + k0),
                (__attribute__((address_space(3))) void*)(ldsA[p] + buf * 8192),
                16, 0, 0);
        #pragma unroll
        for (int p = 0; p < 2; ++p)
            __builtin_amdgcn_global_load_lds(
                (const __attribute__((address_space(1))) void*)(gB[p] + k0),
                (__attribute__((address_space(3))) void*)(ldsB[p] + buf * 4096),
                16, 0, 0);
    };

    // fragment LDS element offsets: chunk c = kk*4 + quad, swizzled by row
    int offA[2][2], offB[4][2];
    #pragma unroll
    for (int mt = 0; mt < 2; ++mt) {
        int r = wave * 32 + mt * 16 + l15;
        #pragma unroll
        for (int kk = 0; kk < 2; ++kk)
            offA[mt][kk] = (r * 8 + (((kk << 2) | quad) ^ (r & 7))) * 8;
    }
    #pragma unroll
    for (int nt = 0; nt < 4; ++nt) {
        int r = nt * 16 + l15;
        #pragma unroll
        for (int kk = 0; kk < 2; ++kk)
            offB[nt][kk] = (r * 8 + (((kk << 2) | quad) ^ (r & 7))) * 8;
    }

    const int niter = K >> 6;   // all callers: K multiple of 64, K >= 128
    stage(0, 0);
    stage(1, 64);
    for (int t = 0; t < niter; ++t) {
        if (t + 1 < niter)
            asm volatile("s_waitcnt vmcnt(6)" ::: "memory");   // keep t+1 in flight
        else
            asm volatile("s_waitcnt vmcnt(0)" ::: "memory");   // last tile
        __builtin_amdgcn_s_barrier();
        const f16* Ab = As + (t & 1) * 8192;
        const f16* Bb = Bs + (t & 1) * 4096;
        f16x8 af[2][2], bf[4][2];
        #pragma unroll
        for (int mt = 0; mt < 2; ++mt)
          #pragma unroll
          for (int kk = 0; kk < 2; ++kk)
            af[mt][kk] = *(const f16x8*)(Ab + offA[mt][kk]);
        #pragma unroll
        for (int nt = 0; nt < 4; ++nt)
          #pragma unroll
          for (int kk = 0; kk < 2; ++kk)
            bf[nt][kk] = *(const f16x8*)(Bb + offB[nt][kk]);
        asm volatile("s_waitcnt lgkmcnt(0)" ::: "memory");  // frags in regs
        __builtin_amdgcn_s_barrier();                        // buf[t&1] free
        if (t + 2 < niter) stage(t & 1, (t + 2) << 6);       // async refill
        #pragma unroll
        for (int kk = 0; kk < 2; ++kk)
          #pragma unroll
          for (int mt = 0; mt < 2; ++mt)
            #pragma unroll
            for (int nt = 0; nt < 4; ++nt)
              acc[mt][nt] = __builtin_amdgcn_mfma_f32_16x16x32_f16(
                  af[mt][kk], bf[nt][kk], acc[mt][nt], 0, 0, 0);
    }
}

// ---------------------------------------------------------------------------
// One recurrent step (also step 0 with A=x0,K=128,W=W_ih):
//   gates = A @ W^T + bias ; cell ; write h (fp16) and c (fp32)
// Block computes [128 batch x 16 hidden] x 4 gates; nt == gate index, so the
// cell runs on registers (i,f,g,o share a lane).
// ---------------------------------------------------------------------------
__global__ __launch_bounds__(256, 2) void k_step(
    const f16* __restrict__ A, int lda, int K,
    const f16* __restrict__ W, int ldb,
    const float* __restrict__ bias,
    float* __restrict__ Cst,
    f16* __restrict__ Hout)
{
    __shared__ alignas(16) f16 As[16384];   // 2 x 128x64
    __shared__ alignas(16) f16 Bs[8192];    // 2 x  64x64
    const int hid0 = blockIdx.x * 16;
    const int bm0  = blockIdx.y * 128;
    f32x4 acc[2][4];
    gemm_core(A, lda, W, ldb, K, bm0, hid0, 2048, As, Bs, acc);

    const int lane = threadIdx.x & 63;
    const int wave = threadIdx.x >> 6;
    const int l15 = lane & 15, quad = lane >> 4;
    const int hid = hid0 + l15;
    const float bI = bias[hid];
    const float bF = bias[2048 + hid];
    const float bG = bias[4096 + hid];
    const float bO = bias[6144 + hid];
    #pragma unroll
    for (int mt = 0; mt < 2; ++mt) {
      #pragma unroll
      for (int reg = 0; reg < 4; ++reg) {
        const int row = bm0 + wave * 32 + mt * 16 + quad * 4 + reg;
        const size_t idx = (size_t)row * 2048 + hid;
        float iv = acc[mt][0][reg] + bI;
        float fv = acc[mt][1][reg] + bF;
        float gv = acc[mt][2][reg] + bG;
        float ov = acc[mt][3][reg] + bO;
        float si = 1.f / (1.f + __expf(-iv));
        float sf = 1.f / (1.f + __expf(-fv));
        float so = 1.f / (1.f + __expf(-ov));
        float tg = tanhf(gv);
        float c = sf * Cst[idx] + si * tg;
        Cst[idx] = c;
        Hout[idx] = (f16)(so * tanhf(c));
      }
    }
}

// out[b, t, d] = H[slot, b, :] @ W_out[d, :] + b_out[d];  t = t0 + slot
__global__ __launch_bounds__(256, 2) void k_out(
    const f16* __restrict__ Hbase,
    const f16* __restrict__ Wout,
    const float* __restrict__ bout,
    float* __restrict__ out, int t0)
{
    __shared__ alignas(16) f16 As[16384];
    __shared__ alignas(16) f16 Bs[8192];
    const int ng  = blockIdx.x;        // 0..1 : 64 output dims each
    const int bm0 = blockIdx.y * 128;  // over M = depth*512
    f32x4 acc[2][4];
    gemm_core(Hbase, 2048, Wout, 2048, 2048, bm0, ng * 64, 16, As, Bs, acc);
    const int lane = threadIdx.x & 63;
    const int wave = threadIdx.x >> 6;
    const int l15 = lane & 15, quad = lane >> 4;
    #pragma unroll
    for (int mt = 0; mt < 2; ++mt) {
      #pragma unroll
      for (int nt = 0; nt < 4; ++nt) {
        const int d = ng * 64 + nt * 16 + l15;
        const float bo = bout[d];
        #pragma unroll
        for (int reg = 0; reg < 4; ++reg) {
          const int m = bm0 + wave * 32 + mt * 16 + quad * 4 + reg;
          const int slot = m >> 9, b = m & 511;
          const int t = t0 + slot;
          out[(size_t)b * 16384 + t * 128 + d] = acc[mt][nt][reg] + bo;
        }
      }
    }
}

// ---------------- prep kernels (run once per launch) ------------------------

__global__ void k_cast(const float* __restrict__ s, f16* __restrict__ d, int n)
{
    int i = blockIdx.x * 256 + threadIdx.x;
    if (i < n) d[i] = (f16)s[i];
}

__global__ void k_x0(const float* __restrict__ tgt, f16* __restrict__ x0)
{
    int i = blockIdx.x * 256 + threadIdx.x;  // 65536 total
    int b = i >> 7, d = i & 127;
    x0[i] = (f16)tgt[(size_t)b * 16384 + d];  // tgt[b, 0, d]
}

__global__ void k_bias(const float* __restrict__ bih, const float* __restrict__ bhh,
                       const float* __restrict__ Wih, const float* __restrict__ bout,
                       float* __restrict__ b0, float* __restrict__ bp)
{
    int r = blockIdx.x * 256 + threadIdx.x;
    if (r >= 8192) return;
    float s = bih[r] + bhh[r];
    float a = 0.f;
    for (int d = 0; d < 128; ++d) a += Wih[(size_t)r * 128 + d] * bout[d];
    b0[r] = s;        // step-0 bias
    bp[r] = s + a;    // recurrent bias (absorbs W_ih @ b_out)
}

// WoutT[k][d] = (f16) Wout[d][k]   (2048 x 128, MFMA B-operand for k_wcomb2)
__global__ void k_wt(const float* __restrict__ Wout, f16* __restrict__ WoutT)
{
    __shared__ float tile[64][65];
    const int k0 = blockIdx.x * 64;   // 32
    const int d0 = blockIdx.y * 64;   // 2
    const int tid = threadIdx.x;
    const int c = tid & 63, rr = tid >> 6;
    #pragma unroll
    for (int i = 0; i < 16; ++i) {
        int d = rr + i * 4;
        tile[d][c] = Wout[(size_t)(d0 + d) * 2048 + k0 + c];
    }
    __syncthreads();
    #pragma unroll
    for (int i = 0; i < 16; ++i) {
        int k = rr + i * 4;
        WoutT[(size_t)(k0 + k) * 128 + d0 + c] = (f16)tile[c][k];
    }
}

// Wc[r,k] = Whh[r,k] + W_ih[r,:] @ W_out[:,k]  via MFMA (was scalar k_wcomb)
__global__ __launch_bounds__(256, 2) void k_wcomb2(
    const f16* __restrict__ Wih16, const f16* __restrict__ WoutT,
    const float* __restrict__ Whh, f16* __restrict__ Wc)
{
    __shared__ alignas(16) f16 As[16384];
    __shared__ alignas(16) f16 Bs[8192];
    const int n0  = blockIdx.x * 64;   // 32 col-blocks over k
    const int bm0 = blockIdx.y * 128;  // 64 row-blocks over r
    f32x4 acc[2][4];
    gemm_core(Wih16, 128, WoutT, 128, 128, bm0, n0, 16, As, Bs, acc);
    const int lane = threadIdx.x & 63;
    const int wave = threadIdx.x >> 6;
    const int l15 = lane & 15, quad = lane >> 4;
    #pragma unroll
    for (int mt = 0; mt < 2; ++mt) {
      #pragma unroll
      for (int nt = 0; nt < 4; ++nt) {
        const int k = n0 + nt * 16 + l15;
        #pragma unroll
        for (int reg = 0; reg < 4; ++reg) {
          const int r = bm0 + wave * 32 + mt * 16 + quad * 4 + reg;
          Wc[(size_t)r * 2048 + k] =
              (f16)(acc[mt][nt][reg] + Whh[(size_t)r * 2048 + k]);
        }
      }
    }
}

// ---------------------------------------------------------------------------

extern "C" void kernel_launch(void* const* d_in, const int* in_sizes, int n_in,
                              void* d_out, int out_size, void* d_ws, size_t ws_size,
                              hipStream_t stream)
{
    const float* tgt  = (const float*)d_in[0];
    const float* Wih  = (const float*)d_in[1];
    const float* Whh  = (const float*)d_in[2];
    const float* bih  = (const float*)d_in[3];
    const float* bhh  = (const float*)d_in[4];
    const float* Wout = (const float*)d_in[5];
    const float* bout = (const float*)d_in[6];
    float* out = (float*)d_out;

    char* ws = (char*)d_ws;
    size_t off = 0;
    auto alloc = [&](size_t bytes) -> void* {
        void* p = ws + off;
        off += (bytes + 255) & ~(size_t)255;
        return p;
    };
    f16*   Wc     = (f16*)alloc((size_t)8192 * 2048 * 2);  // combined W_hh + W_ih*W_out
    f16*   Wih16  = (f16*)alloc((size_t)8192 * 128 * 2);
    f16*   Wout16 = (f16*)alloc((size_t)128 * 2048 * 2);
    f16*   WoutT  = (f16*)alloc((size_t)2048 * 128 * 2);
    f16*   x0     = (f16*)alloc((size_t)512 * 128 * 2);
    float* b0     = (float*)alloc(8192 * 4);
    float* bp     = (float*)alloc(8192 * 4);
    float* Cst    = (float*)alloc((size_t)512 * 2048 * 4);

    const size_t slotsz = (size_t)512 * 2048;  // elements per h snapshot
    int depth = 0;
    const int cands[7] = {128, 64, 32, 16, 8, 4, 2};
    for (int i = 0; i < 7; ++i)
        if (off + (size_t)cands[i] * slotsz * 2 <= ws_size) { depth = cands[i]; break; }
    if (depth == 0) return;  // workspace too small for any configuration
    f16* Hbuf = (f16*)alloc((size_t)depth * slotsz * 2);

    hipMemsetAsync(Cst, 0, (size_t)512 * 2048 * 4, stream);
    k_cast<<<dim3(4096), dim3(256), 0, stream>>>(Wih, Wih16, 1048576);
    k_cast<<<dim3(1024), dim3(256), 0, stream>>>(Wout, Wout16, 262144);
    k_wt<<<dim3(32, 2), dim3(256), 0, stream>>>(Wout, WoutT);
    k_x0<<<dim3(256), dim3(256), 0, stream>>>(tgt, x0);
    k_bias<<<dim3(32), dim3(256), 0, stream>>>(bih, bhh, Wih, bout, b0, bp);
    k_wcomb2<<<dim3(32, 64), dim3(256), 0, stream>>>(Wih16, WoutT, Whh, Wc);

    // step 0: gates = x0 @ W_ih^T + (b_ih+b_hh)  -> h^1 in slot 0
    k_step<<<dim3(128, 4), dim3(256), 0, stream>>>(x0, 128, 128, Wih16, 128, b0, Cst, Hbuf);
    // steps 1..127: gates = h @ W'^T + b'
    for (int s = 1; s < 128; ++s) {
        if ((s % depth) == 0)  // slots 0..depth-1 hold h^(s-depth+1..s) -> out t in [s-depth, s)
            k_out<<<dim3(2, depth * 4), dim3(256), 0, stream>>>(Hbuf, Wout16, bout, out, s - depth);
        k_step<<<dim3(128, 4), dim3(256), 0, stream>>>(
            Hbuf + (size_t)((s - 1) % depth) * slotsz, 2048, 2048, Wc, 2048, bp,
            Cst, Hbuf + (size_t)(s % depth) * slotsz);
    }
    k_out<<<dim3(2, depth * 4), dim3(256), 0, stream>>>(Hbuf, Wout16, bout, out, 128 - depth);
}